// Round 20
// baseline (62.020 us; speedup 1.0000x reference)
//
#include <hip/hip_runtime.h>
#include <hip/hip_bf16.h>
#include <math.h>

#define NB 4
#define NT 4096
#define NC 1024
#define NH 64
#define NCH 144   // chunks/batch: 8-tile chunks over 32 q-tiles (128 rows each)

typedef __attribute__((ext_vector_type(8))) short short8;
typedef __attribute__((ext_vector_type(4))) float f32x4;
typedef __attribute__((ext_vector_type(8))) unsigned short ushort8v;
typedef __attribute__((ext_vector_type(4))) unsigned short ushort4v;

static __device__ __forceinline__ unsigned short f2bf(float f) {
    union { __hip_bfloat16 b; unsigned short u; } cv;
    cv.b = __float2bfloat16(f);
    return cv.u;
}
static __device__ __forceinline__ float bf2f(unsigned short u) {
    union { unsigned int i; float f; } cv;
    cv.i = ((unsigned int)u) << 16;
    return cv.f;
}

// ---------------- W prep: Wt[m][h][k] bf16, m in {K,Q,V} ----------------
__global__ __launch_bounds__(256) void wprep_kernel(
    const float* __restrict__ Wk,
    const float* __restrict__ Wq,
    const float* __restrict__ Wv,
    unsigned short* __restrict__ wt)
{
    __shared__ float tile[64][65];
    const int m  = blockIdx.x >> 4;
    const int k0 = (blockIdx.x & 15) << 6;
    const float* __restrict__ W = (m == 0) ? Wk : (m == 1) ? Wq : Wv;
    const float qs = (m == 1) ? 0.125f * 1.44269504f : 1.0f;
    const int tid = threadIdx.x;
    const int c   = tid & 63;
    for (int i = tid >> 6; i < 64; i += 4)
        tile[i][c] = W[(size_t)(k0 + i) * NH + c];
    __syncthreads();
    const int i0 = (tid >> 6) * 16;
    unsigned short* dst = wt + ((size_t)m * 64 + c) * NC + k0 + i0;
    ushort8v a, b;
#pragma unroll
    for (int j = 0; j < 8; ++j) a[j] = f2bf(tile[i0 + j][c] * qs);
#pragma unroll
    for (int j = 0; j < 8; ++j) b[j] = f2bf(tile[i0 + 8 + j][c] * qs);
    *reinterpret_cast<ushort8v*>(dst)     = a;
    *reinterpret_cast<ushort8v*>(dst + 8) = b;
}

// ---------------- projection GEMM: 32 rows, SINGLE-buffered x+W LDS -------
// Loads are register-double-buffered (issued one chunk ahead, full
// COMPUTE+barrier of slack); LDS is single-buffered with writes fenced
// between two barriers (nothing reads LDS in that window). LDS 56->28 KB
// => 4 blocks/CU (launch_bounds(256,4), VGPR cap 128) — 2x co-tenancy to
// hide the x HBM latency. Per-wave instruction stream unchanged vs R13.
__global__ __launch_bounds__(256, 4) void proj_kernel(
    const float* __restrict__ x,
    const unsigned short* __restrict__ wt,
    unsigned short* __restrict__ ko,
    unsigned short* __restrict__ qo,
    unsigned short* __restrict__ vt)
{
    __shared__ unsigned short xsb[32 * 64];    // 4 KB bf16, swizzled
    __shared__ unsigned short wsb[192 * 64];   // 24 KB bf16, swizzled

    const int tid  = threadIdx.x;
    const int wid  = tid >> 6;
    const int lane = tid & 63;
    const int l15  = lane & 15;
    const int hi   = lane >> 4;
    const int t0   = blockIdx.x << 5;

    const int srow = tid >> 3;
    const int sg   = tid & 7;
    const int ssw  = sg ^ (srow & 7);
    const float* __restrict__ xsrc = x + (size_t)(t0 + srow) * NC + sg * 8;
    unsigned short* const sdst = &xsb[srow * 64 + ssw * 8];

    int wrow[6], wsl[6];
#pragma unroll
    for (int it = 0; it < 6; ++it) {
        const int F = it * 256 + tid;
        wrow[it] = F >> 3;
        wsl[it]  = F & 7;
    }

    int mm[3], hr[3];
#pragma unroll
    for (int f = 0; f < 3; ++f) {
        const int hc = wid * 48 + f * 16;
        mm[f] = hc >> 6;
        hr[f] = hc & 63;
    }

    f32x4 acc[2][3];
#pragma unroll
    for (int mf = 0; mf < 2; ++mf)
#pragma unroll
        for (int f = 0; f < 3; ++f) acc[mf][f] = (f32x4){0.f, 0.f, 0.f, 0.f};

    auto XWRITE = [&](const f32x4& a, const f32x4& b) {
        ushort8v pk;
        pk[0] = f2bf(a[0]); pk[1] = f2bf(a[1]);
        pk[2] = f2bf(a[2]); pk[3] = f2bf(a[3]);
        pk[4] = f2bf(b[0]); pk[5] = f2bf(b[1]);
        pk[6] = f2bf(b[2]); pk[7] = f2bf(b[3]);
        *reinterpret_cast<ushort8v*>(sdst) = pk;
    };

    auto WSTORE = [&](const short8 (&wr)[6]) {
#pragma unroll
        for (int it = 0; it < 6; ++it) {
            const int dst = wrow[it] * 64 + ((wsl[it] ^ (wrow[it] & 7)) << 3);
            *reinterpret_cast<short8*>(&wsb[dst]) = wr[it];
        }
    };

    auto COMPUTE = [&]() {
        short8 xf[2][2];
#pragma unroll
        for (int mf = 0; mf < 2; ++mf) {
            const int row = mf * 16 + l15;
#pragma unroll
            for (int ks = 0; ks < 2; ++ks) {
                const int sw = (ks * 4 + hi) ^ (row & 7);
                xf[mf][ks] = *reinterpret_cast<const short8*>(
                    &xsb[row * 64 + sw * 8]);
            }
        }
#pragma unroll
        for (int f = 0; f < 3; ++f) {
            const int wr = wid * 48 + f * 16 + l15;
            const int r7 = l15 & 7;
#pragma unroll
            for (int ks = 0; ks < 2; ++ks) {
                const short8 wf = *reinterpret_cast<const short8*>(
                    &wsb[wr * 64 + (((hi + ks * 4) ^ r7) << 3)]);
                if (mm[f] == 2) {
#pragma unroll
                    for (int mf = 0; mf < 2; ++mf)
                        acc[mf][f] = __builtin_amdgcn_mfma_f32_16x16x32_bf16(
                            xf[mf][ks], wf, acc[mf][f], 0, 0, 0);
                } else {
#pragma unroll
                    for (int mf = 0; mf < 2; ++mf)
                        acc[mf][f] = __builtin_amdgcn_mfma_f32_16x16x32_bf16(
                            wf, xf[mf][ks], acc[mf][f], 0, 0, 0);
                }
            }
        }
    };

    // prologue: stage chunk 0 (x + W)
    {
        const f32x4 a = *reinterpret_cast<const f32x4*>(xsrc);
        const f32x4 b = *reinterpret_cast<const f32x4*>(xsrc + 4);
        XWRITE(a, b);
        short8 wr[6];
#pragma unroll
        for (int it = 0; it < 6; ++it)
            wr[it] = *reinterpret_cast<const short8*>(
                wt + (size_t)wrow[it] * NC + wsl[it] * 8);
        WSTORE(wr);
    }
    __syncthreads();

    for (int ck = 0; ck < 16; ++ck) {
        f32x4 na, nb;
        short8 wr[6];
        if (ck < 15) {                     // issue next-chunk loads early
            const float* p = xsrc + (ck + 1) * 64;
            na = *reinterpret_cast<const f32x4*>(p);
            nb = *reinterpret_cast<const f32x4*>(p + 4);
#pragma unroll
            for (int it = 0; it < 6; ++it)
                wr[it] = *reinterpret_cast<const short8*>(
                    wt + (size_t)wrow[it] * NC + (ck + 1) * 64 + wsl[it] * 8);
        }
        COMPUTE();
        if (ck < 15) {
            __syncthreads();               // all waves done reading LDS
            XWRITE(na, nb);
            WSTORE(wr);
            __syncthreads();               // stores visible
        }
    }

    const int b  = t0 >> 12;
    const int tl = t0 & (NT - 1);
#pragma unroll
    for (int f = 0; f < 3; ++f) {
#pragma unroll
        for (int mf = 0; mf < 2; ++mf) {
            const f32x4 a = acc[mf][f];
            ushort4v pk;
            pk[0] = f2bf(a[0]); pk[1] = f2bf(a[1]);
            pk[2] = f2bf(a[2]); pk[3] = f2bf(a[3]);
            if (mm[f] == 2) {
                unsigned short* d = vt + ((size_t)(b * NH + hr[f] + l15)) * NT
                                       + tl + mf * 16 + hi * 4;
                *reinterpret_cast<ushort4v*>(d) = pk;
            } else {
                unsigned short* o = (mm[f] == 0) ? ko : qo;
                unsigned short* d = o + (size_t)(t0 + mf * 16 + l15) * NH
                                      + hr[f] + hi * 4;
                *reinterpret_cast<ushort4v*>(d) = pk;
            }
        }
    }
}

// ---------------- MFMA flash attention, shared-LDS K/V, chunked (R19) -----
__global__ __launch_bounds__(512) void attn_kernel(
    const unsigned short* __restrict__ kin,
    const unsigned short* __restrict__ qin,
    const unsigned short* __restrict__ vt,
    unsigned short* __restrict__ part)
{
    __shared__ unsigned short ksb[2][64 * 64];
    __shared__ unsigned short vsb[2][64 * 64];
    __shared__ unsigned short p_lds[8][16 * 72];

    const int tid  = threadIdx.x;
    const int wid  = tid >> 6;
    const int lane = tid & 63;
    const int q15  = lane & 15;
    const int hi   = lane >> 4;

    const int bid  = blockIdx.x;
    const int xcd  = bid & 7;
    const int b    = xcd >> 1;
    const int clin = ((bid >> 3) << 1) | (xcd & 1);
    const int c    = (NCH - 1) - clin;

    int qi = 0, basei = 0;
    for (int t = 31; t >= 0; --t) {
        const int g = t >> 2, r = t & 3;
        const int bs = t + 2 * g * (g - 1) + r * g;
        if (bs <= c) { qi = t; basei = bs; break; }
    }
    const int k     = c - basei;
    const int n_blk = 2 * qi + 2;
    const int jb0   = k * 8;
    const int jend  = min(jb0 + 8, n_blk);
    const int n_w   = 2 * qi + 1 + (wid >> 2);

    const unsigned short* kb = kin + (size_t)b * NT * NH;
    const unsigned short* qb = qin + (size_t)b * NT * NH;
    const unsigned short* vb = vt  + (size_t)b * NH * NT;

    const int gq = qi * 128 + wid * 16 + q15;

    short8 qf0, qf1;
    {
        const unsigned short* qrow = qb + (size_t)gq * NH + hi * 8;
        qf0 = *reinterpret_cast<const short8*>(qrow);
        qf1 = *reinterpret_cast<const short8*>(qrow + 32);
    }

    const int srow = tid >> 3;
    const int sg   = tid & 7;
    const int sdst = srow * 64 + (sg ^ (srow & 7)) * 8;
    const unsigned short* kstat = kb + (size_t)srow * NH + sg * 8;
    const unsigned short* vstat = vb + (size_t)srow * NT + sg * 8;

    f32x4 ot[4];
#pragma unroll
    for (int i = 0; i < 4; ++i) ot[i] = (f32x4){0.f, 0.f, 0.f, 0.f};
    float m = 0.f, lp = 0.f;

    {
        const short8 kr = *reinterpret_cast<const short8*>(kstat + (size_t)jb0 * 4096);
        const short8 vr = *reinterpret_cast<const short8*>(vstat + jb0 * 64);
        *reinterpret_cast<short8*>(&ksb[0][sdst]) = kr;
        *reinterpret_cast<short8*>(&vsb[0][sdst]) = vr;
    }
    __syncthreads();

    int cur = 0;
    for (int jb = jb0; jb < jend; ++jb) {
        const bool more = (jb + 1 < jend);
        short8 knx, vnx;
        if (more) {
            knx = *reinterpret_cast<const short8*>(kstat + (size_t)(jb + 1) * 4096);
            vnx = *reinterpret_cast<const short8*>(vstat + (jb + 1) * 64);
        }

        if (jb < n_w) {
            const int kv0 = jb << 6;
            const int r7  = q15 & 7;

            f32x4 st[4];
            __builtin_amdgcn_s_setprio(1);
#pragma unroll
            for (int kt = 0; kt < 4; ++kt) {
                const int rb = (kt * 16 + q15) * 64;
                const short8 ka0 = *reinterpret_cast<const short8*>(
                    &ksb[cur][rb + ((hi ^ r7) * 8)]);
                const short8 ka1 = *reinterpret_cast<const short8*>(
                    &ksb[cur][rb + (((4 + hi) ^ r7) * 8)]);
                f32x4 acc = (f32x4){0.f, 0.f, 0.f, 0.f};
                acc = __builtin_amdgcn_mfma_f32_16x16x32_bf16(ka0, qf0, acc, 0, 0, 0);
                acc = __builtin_amdgcn_mfma_f32_16x16x32_bf16(ka1, qf1, acc, 0, 0, 0);
                st[kt] = acc;
            }
            __builtin_amdgcn_s_setprio(0);

            float tmax4 = -INFINITY;
            if (jb == n_w - 1) {
#pragma unroll
                for (int kt = 0; kt < 4; ++kt)
#pragma unroll
                    for (int r = 0; r < 4; ++r) {
                        const int gk = kv0 + kt * 16 + hi * 4 + r;
                        const float s = (gk <= gq) ? st[kt][r] : -INFINITY;
                        st[kt][r] = s;
                        tmax4 = fmaxf(tmax4, s);
                    }
            } else {
#pragma unroll
                for (int kt = 0; kt < 4; ++kt)
#pragma unroll
                    for (int r = 0; r < 4; ++r)
                        tmax4 = fmaxf(tmax4, st[kt][r]);
            }

            if (!__all(tmax4 <= m + 11.5f)) {
                float tm = fmaxf(tmax4, __shfl_xor(tmax4, 16));
                tm = fmaxf(tm, __shfl_xor(tm, 32));
                const float mnew = fmaxf(m, tm);
                const float corr = __builtin_amdgcn_exp2f(m - mnew);
                lp *= corr;
#pragma unroll
                for (int i = 0; i < 4; ++i) {
                    ot[i][0] *= corr; ot[i][1] *= corr;
                    ot[i][2] *= corr; ot[i][3] *= corr;
                }
                m = mnew;
            }

#pragma unroll
            for (int kt = 0; kt < 4; ++kt) {
                const float p0 = __builtin_amdgcn_exp2f(st[kt][0] - m);
                const float p1 = __builtin_amdgcn_exp2f(st[kt][1] - m);
                const float p2 = __builtin_amdgcn_exp2f(st[kt][2] - m);
                const float p3 = __builtin_amdgcn_exp2f(st[kt][3] - m);
                lp += (p0 + p1) + (p2 + p3);
                ushort4v pk;
                pk[0] = f2bf(p0); pk[1] = f2bf(p1);
                pk[2] = f2bf(p2); pk[3] = f2bf(p3);
                *reinterpret_cast<ushort4v*>(&p_lds[wid][q15 * 72 + kt * 16 + hi * 4]) = pk;
            }

            const short8 pb0 = *reinterpret_cast<const short8*>(&p_lds[wid][q15 * 72 + hi * 8]);
            const short8 pb1 = *reinterpret_cast<const short8*>(&p_lds[wid][q15 * 72 + 32 + hi * 8]);
            __builtin_amdgcn_s_setprio(1);
#pragma unroll
            for (int ht = 0; ht < 4; ++ht) {
                const int rb = (ht * 16 + q15) * 64;
                const short8 va0 = *reinterpret_cast<const short8*>(
                    &vsb[cur][rb + ((hi ^ r7) * 8)]);
                const short8 va1 = *reinterpret_cast<const short8*>(
                    &vsb[cur][rb + (((4 + hi) ^ r7) * 8)]);
                ot[ht] = __builtin_amdgcn_mfma_f32_16x16x32_bf16(va0, pb0, ot[ht], 0, 0, 0);
                ot[ht] = __builtin_amdgcn_mfma_f32_16x16x32_bf16(va1, pb1, ot[ht], 0, 0, 0);
            }
            __builtin_amdgcn_s_setprio(0);
        }

        if (more) {
            *reinterpret_cast<short8*>(&ksb[cur ^ 1][sdst]) = knx;
            *reinterpret_cast<short8*>(&vsb[cur ^ 1][sdst]) = vnx;
        }
        __syncthreads();
        cur ^= 1;
    }

    float l = lp + __shfl_xor(lp, 16);
    l += __shfl_xor(l, 32);
    unsigned short* pp = part + (((size_t)b * NCH + c) * 128 + wid * 16 + q15) * 72;
#pragma unroll
    for (int ht = 0; ht < 4; ++ht) {
        ushort4v pk;
        pk[0] = f2bf(ot[ht][0]); pk[1] = f2bf(ot[ht][1]);
        pk[2] = f2bf(ot[ht][2]); pk[3] = f2bf(ot[ht][3]);
        *reinterpret_cast<ushort4v*>(pp + ht * 16 + hi * 4) = pk;
    }
    if (hi == 0) {
        *reinterpret_cast<float*>(pp + 64) = m;
        *reinterpret_cast<float*>(pp + 66) = l;
    }
}

// ---------------- combine chunk partials (bf16 O, f32 m/l) ----------------
__global__ __launch_bounds__(256) void comb_kernel(
    const unsigned short* __restrict__ part,
    float* __restrict__ outp)
{
    const int tid = threadIdx.x;
    const int bid = blockIdx.x;
    const int b   = bid >> 10;
    const int lr  = ((bid & 1023) << 2) + (tid >> 6);
    const int h   = tid & 63;
    const int qi  = lr >> 7;
    const int g   = qi >> 2, r = qi & 3;
    const int basei = qi + 2 * g * (g - 1) + r * g;
    const int nch   = (qi >> 2) + 1;
    const unsigned short* p0 = part + (((size_t)b * NCH + basei) * 128 + (lr & 127)) * 72;

    float mg = -INFINITY;
    for (int ch = 0; ch < nch; ++ch)
        mg = fmaxf(mg, *reinterpret_cast<const float*>(p0 + (size_t)ch * 128 * 72 + 64));
    float L = 0.f, o = 0.f;
    for (int ch = 0; ch < nch; ++ch) {
        const unsigned short* pc = p0 + (size_t)ch * 128 * 72;
        const float mc = *reinterpret_cast<const float*>(pc + 64);
        const float lc = *reinterpret_cast<const float*>(pc + 66);
        const float w  = __builtin_amdgcn_exp2f(mc - mg);
        L += w * lc;
        o += w * bf2f(pc[h]);
    }
    outp[((size_t)b * NT + lr) * NH + h] = o / L;
}

extern "C" void kernel_launch(void* const* d_in, const int* in_sizes, int n_in,
                              void* d_out, int out_size, void* d_ws, size_t ws_size,
                              hipStream_t stream) {
    const float* x  = (const float*)d_in[0];
    const float* Wk = (const float*)d_in[1];
    const float* Wq = (const float*)d_in[2];
    const float* Wv = (const float*)d_in[3];
    float* out = (float*)d_out;

    unsigned short* kbuf = (unsigned short*)d_ws;              // [B*T][64] bf16
    unsigned short* qbuf = kbuf + (size_t)NB * NT * NH;        // [B*T][64] bf16
    unsigned short* vtbf = qbuf + (size_t)NB * NT * NH;        // [B][64][T] bf16
    unsigned short* wtbf = vtbf + (size_t)NB * NT * NH;        // [3][64][1024] bf16
    unsigned short* part = wtbf + (size_t)3 * 64 * NC;         // [B][144][128][72] ushort

    wprep_kernel<<<48, 256, 0, stream>>>(Wk, Wq, Wv, wtbf);
    proj_kernel<<<NB * NT / 32, 256, 0, stream>>>(x, wtbf, kbuf, qbuf, vtbf);
    attn_kernel<<<576, 512, 0, stream>>>(kbuf, qbuf, vtbf, part);
    comb_kernel<<<4096, 256, 0, stream>>>(part, out);
}

// Round 21
// 61.583 us; speedup vs baseline: 1.0071x; 1.0071x over previous
//
#include <hip/hip_runtime.h>
#include <hip/hip_bf16.h>
#include <math.h>

#define NB 4
#define NT 4096
#define NC 1024
#define NH 64
#define NCH 144   // chunks/batch: 8-tile chunks over 32 q-tiles (128 rows each)

typedef __attribute__((ext_vector_type(8))) short short8;
typedef __attribute__((ext_vector_type(4))) float f32x4;
typedef __attribute__((ext_vector_type(8))) unsigned short ushort8v;
typedef __attribute__((ext_vector_type(4))) unsigned short ushort4v;

static __device__ __forceinline__ unsigned short f2bf(float f) {
    union { __hip_bfloat16 b; unsigned short u; } cv;
    cv.b = __float2bfloat16(f);
    return cv.u;
}
static __device__ __forceinline__ float bf2f(unsigned short u) {
    union { unsigned int i; float f; } cv;
    cv.i = ((unsigned int)u) << 16;
    return cv.f;
}

// ---------------- W prep: Wt[m][h][k] bf16, m in {K,Q,V} ----------------
__global__ __launch_bounds__(256) void wprep_kernel(
    const float* __restrict__ Wk,
    const float* __restrict__ Wq,
    const float* __restrict__ Wv,
    unsigned short* __restrict__ wt)
{
    __shared__ float tile[64][65];
    const int m  = blockIdx.x >> 4;
    const int k0 = (blockIdx.x & 15) << 6;
    const float* __restrict__ W = (m == 0) ? Wk : (m == 1) ? Wq : Wv;
    const float qs = (m == 1) ? 0.125f * 1.44269504f : 1.0f;
    const int tid = threadIdx.x;
    const int c   = tid & 63;
    for (int i = tid >> 6; i < 64; i += 4)
        tile[i][c] = W[(size_t)(k0 + i) * NH + c];
    __syncthreads();
    const int i0 = (tid >> 6) * 16;
    unsigned short* dst = wt + ((size_t)m * 64 + c) * NC + k0 + i0;
    ushort8v a, b;
#pragma unroll
    for (int j = 0; j < 8; ++j) a[j] = f2bf(tile[i0 + j][c] * qs);
#pragma unroll
    for (int j = 0; j < 8; ++j) b[j] = f2bf(tile[i0 + 8 + j][c] * qs);
    *reinterpret_cast<ushort8v*>(dst)     = a;
    *reinterpret_cast<ushort8v*>(dst + 8) = b;
}

// ---------------- projection GEMM: 32 rows, x AND W staged in LDS (R13) ---
// + s_setprio around the MFMA cluster (2 blocks/CU at staggered phases).
__global__ __launch_bounds__(256, 2) void proj_kernel(
    const float* __restrict__ x,
    const unsigned short* __restrict__ wt,
    unsigned short* __restrict__ ko,
    unsigned short* __restrict__ qo,
    unsigned short* __restrict__ vt)
{
    __shared__ unsigned short xsb[2][32 * 64];    // 2 x 4 KB bf16, swizzled
    __shared__ unsigned short wsb[2][192 * 64];   // 2 x 24 KB bf16, swizzled

    const int tid  = threadIdx.x;
    const int wid  = tid >> 6;
    const int lane = tid & 63;
    const int l15  = lane & 15;
    const int hi   = lane >> 4;
    const int t0   = blockIdx.x << 5;

    const int srow = tid >> 3;
    const int sg   = tid & 7;
    const int ssw  = sg ^ (srow & 7);
    const float* __restrict__ xsrc = x + (size_t)(t0 + srow) * NC + sg * 8;
    unsigned short* const sdst0 = &xsb[0][srow * 64 + ssw * 8];
    unsigned short* const sdst1 = &xsb[1][srow * 64 + ssw * 8];

    int wrow[6], wsl[6];
#pragma unroll
    for (int it = 0; it < 6; ++it) {
        const int F = it * 256 + tid;
        wrow[it] = F >> 3;
        wsl[it]  = F & 7;
    }

    int mm[3], hr[3];
#pragma unroll
    for (int f = 0; f < 3; ++f) {
        const int hc = wid * 48 + f * 16;
        mm[f] = hc >> 6;
        hr[f] = hc & 63;
    }

    f32x4 acc[2][3];
#pragma unroll
    for (int mf = 0; mf < 2; ++mf)
#pragma unroll
        for (int f = 0; f < 3; ++f) acc[mf][f] = (f32x4){0.f, 0.f, 0.f, 0.f};

    auto XWRITE = [&](unsigned short* dst, const f32x4& a, const f32x4& b) {
        ushort8v pk;
        pk[0] = f2bf(a[0]); pk[1] = f2bf(a[1]);
        pk[2] = f2bf(a[2]); pk[3] = f2bf(a[3]);
        pk[4] = f2bf(b[0]); pk[5] = f2bf(b[1]);
        pk[6] = f2bf(b[2]); pk[7] = f2bf(b[3]);
        *reinterpret_cast<ushort8v*>(dst) = pk;
    };

    auto WSTORE = [&](int bi, const short8 (&wr)[6]) {
#pragma unroll
        for (int it = 0; it < 6; ++it) {
            const int dst = wrow[it] * 64 + ((wsl[it] ^ (wrow[it] & 7)) << 3);
            *reinterpret_cast<short8*>(&wsb[bi][dst]) = wr[it];
        }
    };

    auto COMPUTE = [&](int bi) {
        short8 xf[2][2];
#pragma unroll
        for (int mf = 0; mf < 2; ++mf) {
            const int row = mf * 16 + l15;
#pragma unroll
            for (int ks = 0; ks < 2; ++ks) {
                const int sw = (ks * 4 + hi) ^ (row & 7);
                xf[mf][ks] = *reinterpret_cast<const short8*>(
                    &xsb[bi][row * 64 + sw * 8]);
            }
        }
        __builtin_amdgcn_s_setprio(1);
#pragma unroll
        for (int f = 0; f < 3; ++f) {
            const int wr = wid * 48 + f * 16 + l15;
            const int r7 = l15 & 7;
#pragma unroll
            for (int ks = 0; ks < 2; ++ks) {
                const short8 wf = *reinterpret_cast<const short8*>(
                    &wsb[bi][wr * 64 + (((hi + ks * 4) ^ r7) << 3)]);
                if (mm[f] == 2) {
#pragma unroll
                    for (int mf = 0; mf < 2; ++mf)
                        acc[mf][f] = __builtin_amdgcn_mfma_f32_16x16x32_bf16(
                            xf[mf][ks], wf, acc[mf][f], 0, 0, 0);
                } else {
#pragma unroll
                    for (int mf = 0; mf < 2; ++mf)
                        acc[mf][f] = __builtin_amdgcn_mfma_f32_16x16x32_bf16(
                            wf, xf[mf][ks], acc[mf][f], 0, 0, 0);
                }
            }
        }
        __builtin_amdgcn_s_setprio(0);
    };

    {
        const f32x4 a = *reinterpret_cast<const f32x4*>(xsrc);
        const f32x4 b = *reinterpret_cast<const f32x4*>(xsrc + 4);
        XWRITE(sdst0, a, b);
        short8 wr[6];
#pragma unroll
        for (int it = 0; it < 6; ++it)
            wr[it] = *reinterpret_cast<const short8*>(
                wt + (size_t)wrow[it] * NC + wsl[it] * 8);
        WSTORE(0, wr);
    }
    __syncthreads();

    for (int ck = 0; ck < 16; ++ck) {
        const int cur = ck & 1;
        f32x4 na, nb;
        short8 wr[6];
        if (ck < 15) {
            const float* p = xsrc + (ck + 1) * 64;
            na = *reinterpret_cast<const f32x4*>(p);
            nb = *reinterpret_cast<const f32x4*>(p + 4);
#pragma unroll
            for (int it = 0; it < 6; ++it)
                wr[it] = *reinterpret_cast<const short8*>(
                    wt + (size_t)wrow[it] * NC + (ck + 1) * 64 + wsl[it] * 8);
        }
        COMPUTE(cur);
        if (ck < 15) {
            XWRITE(cur ? sdst0 : sdst1, na, nb);
            WSTORE(cur ^ 1, wr);
        }
        __syncthreads();
    }

    const int b  = t0 >> 12;
    const int tl = t0 & (NT - 1);
#pragma unroll
    for (int f = 0; f < 3; ++f) {
#pragma unroll
        for (int mf = 0; mf < 2; ++mf) {
            const f32x4 a = acc[mf][f];
            ushort4v pk;
            pk[0] = f2bf(a[0]); pk[1] = f2bf(a[1]);
            pk[2] = f2bf(a[2]); pk[3] = f2bf(a[3]);
            if (mm[f] == 2) {
                unsigned short* d = vt + ((size_t)(b * NH + hr[f] + l15)) * NT
                                       + tl + mf * 16 + hi * 4;
                *reinterpret_cast<ushort4v*>(d) = pk;
            } else {
                unsigned short* o = (mm[f] == 0) ? ko : qo;
                unsigned short* d = o + (size_t)(t0 + mf * 16 + l15) * NH
                                      + hr[f] + hi * 4;
                *reinterpret_cast<ushort4v*>(d) = pk;
            }
        }
    }
}

// ---------------- MFMA flash attention, shared-LDS K/V, chunked (R19) -----
__global__ __launch_bounds__(512) void attn_kernel(
    const unsigned short* __restrict__ kin,
    const unsigned short* __restrict__ qin,
    const unsigned short* __restrict__ vt,
    unsigned short* __restrict__ part)
{
    __shared__ unsigned short ksb[2][64 * 64];
    __shared__ unsigned short vsb[2][64 * 64];
    __shared__ unsigned short p_lds[8][16 * 72];

    const int tid  = threadIdx.x;
    const int wid  = tid >> 6;
    const int lane = tid & 63;
    const int q15  = lane & 15;
    const int hi   = lane >> 4;

    const int bid  = blockIdx.x;
    const int xcd  = bid & 7;
    const int b    = xcd >> 1;
    const int clin = ((bid >> 3) << 1) | (xcd & 1);
    const int c    = (NCH - 1) - clin;

    int qi = 0, basei = 0;
    for (int t = 31; t >= 0; --t) {
        const int g = t >> 2, r = t & 3;
        const int bs = t + 2 * g * (g - 1) + r * g;
        if (bs <= c) { qi = t; basei = bs; break; }
    }
    const int k     = c - basei;
    const int n_blk = 2 * qi + 2;
    const int jb0   = k * 8;
    const int jend  = min(jb0 + 8, n_blk);
    const int n_w   = 2 * qi + 1 + (wid >> 2);

    const unsigned short* kb = kin + (size_t)b * NT * NH;
    const unsigned short* qb = qin + (size_t)b * NT * NH;
    const unsigned short* vb = vt  + (size_t)b * NH * NT;

    const int gq = qi * 128 + wid * 16 + q15;

    short8 qf0, qf1;
    {
        const unsigned short* qrow = qb + (size_t)gq * NH + hi * 8;
        qf0 = *reinterpret_cast<const short8*>(qrow);
        qf1 = *reinterpret_cast<const short8*>(qrow + 32);
    }

    const int srow = tid >> 3;
    const int sg   = tid & 7;
    const int sdst = srow * 64 + (sg ^ (srow & 7)) * 8;
    const unsigned short* kstat = kb + (size_t)srow * NH + sg * 8;
    const unsigned short* vstat = vb + (size_t)srow * NT + sg * 8;

    f32x4 ot[4];
#pragma unroll
    for (int i = 0; i < 4; ++i) ot[i] = (f32x4){0.f, 0.f, 0.f, 0.f};
    float m = 0.f, lp = 0.f;

    {
        const short8 kr = *reinterpret_cast<const short8*>(kstat + (size_t)jb0 * 4096);
        const short8 vr = *reinterpret_cast<const short8*>(vstat + jb0 * 64);
        *reinterpret_cast<short8*>(&ksb[0][sdst]) = kr;
        *reinterpret_cast<short8*>(&vsb[0][sdst]) = vr;
    }
    __syncthreads();

    int cur = 0;
    for (int jb = jb0; jb < jend; ++jb) {
        const bool more = (jb + 1 < jend);
        short8 knx, vnx;
        if (more) {
            knx = *reinterpret_cast<const short8*>(kstat + (size_t)(jb + 1) * 4096);
            vnx = *reinterpret_cast<const short8*>(vstat + (jb + 1) * 64);
        }

        if (jb < n_w) {
            const int kv0 = jb << 6;
            const int r7  = q15 & 7;

            f32x4 st[4];
            __builtin_amdgcn_s_setprio(1);
#pragma unroll
            for (int kt = 0; kt < 4; ++kt) {
                const int rb = (kt * 16 + q15) * 64;
                const short8 ka0 = *reinterpret_cast<const short8*>(
                    &ksb[cur][rb + ((hi ^ r7) * 8)]);
                const short8 ka1 = *reinterpret_cast<const short8*>(
                    &ksb[cur][rb + (((4 + hi) ^ r7) * 8)]);
                f32x4 acc = (f32x4){0.f, 0.f, 0.f, 0.f};
                acc = __builtin_amdgcn_mfma_f32_16x16x32_bf16(ka0, qf0, acc, 0, 0, 0);
                acc = __builtin_amdgcn_mfma_f32_16x16x32_bf16(ka1, qf1, acc, 0, 0, 0);
                st[kt] = acc;
            }
            __builtin_amdgcn_s_setprio(0);

            float tmax4 = -INFINITY;
            if (jb == n_w - 1) {
#pragma unroll
                for (int kt = 0; kt < 4; ++kt)
#pragma unroll
                    for (int r = 0; r < 4; ++r) {
                        const int gk = kv0 + kt * 16 + hi * 4 + r;
                        const float s = (gk <= gq) ? st[kt][r] : -INFINITY;
                        st[kt][r] = s;
                        tmax4 = fmaxf(tmax4, s);
                    }
            } else {
#pragma unroll
                for (int kt = 0; kt < 4; ++kt)
#pragma unroll
                    for (int r = 0; r < 4; ++r)
                        tmax4 = fmaxf(tmax4, st[kt][r]);
            }

            if (!__all(tmax4 <= m + 11.5f)) {
                float tm = fmaxf(tmax4, __shfl_xor(tmax4, 16));
                tm = fmaxf(tm, __shfl_xor(tm, 32));
                const float mnew = fmaxf(m, tm);
                const float corr = __builtin_amdgcn_exp2f(m - mnew);
                lp *= corr;
#pragma unroll
                for (int i = 0; i < 4; ++i) {
                    ot[i][0] *= corr; ot[i][1] *= corr;
                    ot[i][2] *= corr; ot[i][3] *= corr;
                }
                m = mnew;
            }

#pragma unroll
            for (int kt = 0; kt < 4; ++kt) {
                const float p0 = __builtin_amdgcn_exp2f(st[kt][0] - m);
                const float p1 = __builtin_amdgcn_exp2f(st[kt][1] - m);
                const float p2 = __builtin_amdgcn_exp2f(st[kt][2] - m);
                const float p3 = __builtin_amdgcn_exp2f(st[kt][3] - m);
                lp += (p0 + p1) + (p2 + p3);
                ushort4v pk;
                pk[0] = f2bf(p0); pk[1] = f2bf(p1);
                pk[2] = f2bf(p2); pk[3] = f2bf(p3);
                *reinterpret_cast<ushort4v*>(&p_lds[wid][q15 * 72 + kt * 16 + hi * 4]) = pk;
            }

            const short8 pb0 = *reinterpret_cast<const short8*>(&p_lds[wid][q15 * 72 + hi * 8]);
            const short8 pb1 = *reinterpret_cast<const short8*>(&p_lds[wid][q15 * 72 + 32 + hi * 8]);
            __builtin_amdgcn_s_setprio(1);
#pragma unroll
            for (int ht = 0; ht < 4; ++ht) {
                const int rb = (ht * 16 + q15) * 64;
                const short8 va0 = *reinterpret_cast<const short8*>(
                    &vsb[cur][rb + ((hi ^ r7) * 8)]);
                const short8 va1 = *reinterpret_cast<const short8*>(
                    &vsb[cur][rb + (((4 + hi) ^ r7) * 8)]);
                ot[ht] = __builtin_amdgcn_mfma_f32_16x16x32_bf16(va0, pb0, ot[ht], 0, 0, 0);
                ot[ht] = __builtin_amdgcn_mfma_f32_16x16x32_bf16(va1, pb1, ot[ht], 0, 0, 0);
            }
            __builtin_amdgcn_s_setprio(0);
        }

        if (more) {
            *reinterpret_cast<short8*>(&ksb[cur ^ 1][sdst]) = knx;
            *reinterpret_cast<short8*>(&vsb[cur ^ 1][sdst]) = vnx;
        }
        __syncthreads();
        cur ^= 1;
    }

    float l = lp + __shfl_xor(lp, 16);
    l += __shfl_xor(l, 32);
    unsigned short* pp = part + (((size_t)b * NCH + c) * 128 + wid * 16 + q15) * 72;
#pragma unroll
    for (int ht = 0; ht < 4; ++ht) {
        ushort4v pk;
        pk[0] = f2bf(ot[ht][0]); pk[1] = f2bf(ot[ht][1]);
        pk[2] = f2bf(ot[ht][2]); pk[3] = f2bf(ot[ht][3]);
        *reinterpret_cast<ushort4v*>(pp + ht * 16 + hi * 4) = pk;
    }
    if (hi == 0) {
        *reinterpret_cast<float*>(pp + 64) = m;
        *reinterpret_cast<float*>(pp + 66) = l;
    }
}

// ---------------- combine chunk partials (bf16 O, f32 m/l) ----------------
__global__ __launch_bounds__(256) void comb_kernel(
    const unsigned short* __restrict__ part,
    float* __restrict__ outp)
{
    const int tid = threadIdx.x;
    const int bid = blockIdx.x;
    const int b   = bid >> 10;
    const int lr  = ((bid & 1023) << 2) + (tid >> 6);
    const int h   = tid & 63;
    const int qi  = lr >> 7;
    const int g   = qi >> 2, r = qi & 3;
    const int basei = qi + 2 * g * (g - 1) + r * g;
    const int nch   = (qi >> 2) + 1;
    const unsigned short* p0 = part + (((size_t)b * NCH + basei) * 128 + (lr & 127)) * 72;

    float mg = -INFINITY;
    for (int ch = 0; ch < nch; ++ch)
        mg = fmaxf(mg, *reinterpret_cast<const float*>(p0 + (size_t)ch * 128 * 72 + 64));
    float L = 0.f, o = 0.f;
    for (int ch = 0; ch < nch; ++ch) {
        const unsigned short* pc = p0 + (size_t)ch * 128 * 72;
        const float mc = *reinterpret_cast<const float*>(pc + 64);
        const float lc = *reinterpret_cast<const float*>(pc + 66);
        const float w  = __builtin_amdgcn_exp2f(mc - mg);
        L += w * lc;
        o += w * bf2f(pc[h]);
    }
    outp[((size_t)b * NT + lr) * NH + h] = o / L;
}

extern "C" void kernel_launch(void* const* d_in, const int* in_sizes, int n_in,
                              void* d_out, int out_size, void* d_ws, size_t ws_size,
                              hipStream_t stream) {
    const float* x  = (const float*)d_in[0];
    const float* Wk = (const float*)d_in[1];
    const float* Wq = (const float*)d_in[2];
    const float* Wv = (const float*)d_in[3];
    float* out = (float*)d_out;

    unsigned short* kbuf = (unsigned short*)d_ws;              // [B*T][64] bf16
    unsigned short* qbuf = kbuf + (size_t)NB * NT * NH;        // [B*T][64] bf16
    unsigned short* vtbf = qbuf + (size_t)NB * NT * NH;        // [B][64][T] bf16
    unsigned short* wtbf = vtbf + (size_t)NB * NT * NH;        // [3][64][1024] bf16
    unsigned short* part = wtbf + (size_t)3 * 64 * NC;         // [B][144][128][72] ushort

    wprep_kernel<<<48, 256, 0, stream>>>(Wk, Wq, Wv, wtbf);
    proj_kernel<<<NB * NT / 32, 256, 0, stream>>>(x, wtbf, kbuf, qbuf, vtbf);
    attn_kernel<<<576, 512, 0, stream>>>(kbuf, qbuf, vtbf, part);
    comb_kernel<<<4096, 256, 0, stream>>>(part, out);
}